// Round 10
// baseline (701.043 us; speedup 1.0000x reference)
//
#include <hip/hip_runtime.h>

#define N 8192
#define D 1024

typedef short bf16x8 __attribute__((ext_vector_type(8)));
typedef float f32x4 __attribute__((ext_vector_type(4)));
typedef unsigned short u16;

#define WAITV(n) asm volatile("s_waitcnt vmcnt(" #n ")" ::: "memory")
#define BAR() __builtin_amdgcn_s_barrier()
#define SB() __builtin_amdgcn_sched_barrier(0)
#define PRIO(p) __builtin_amdgcn_s_setprio(p)

// Opaque asm loads: compiler cannot shorten dest lifetimes or elide them,
// so register double-buffers actually materialize. vmcnt managed manually.
#define ALOAD(d, p) \
  asm volatile("global_load_dwordx4 %0, %1, off" : "=&v"(d) : "v"(p))
#define ALOAD2(dh, dl, p) \
  asm volatile("global_load_dwordx4 %0, %2, off\n\t" \
               "global_load_dwordx4 %1, %2, off offset:1024" \
               : "=&v"(dh), "=&v"(dl) : "v"(p))

__device__ __forceinline__ u16 f2bf(float f) {
  unsigned u = __float_as_uint(f);
  u += 0x7FFF + ((u >> 16) & 1);   // RNE to bf16
  return (u16)(u >> 16);
}
__device__ __forceinline__ float bf2f(u16 h) {
  return __uint_as_float(((unsigned)h) << 16);
}

__device__ __forceinline__ void gload_lds16(const void* g, const void* l) {
  __builtin_amdgcn_global_load_lds(
      (const __attribute__((address_space(1))) void*)g,
      (__attribute__((address_space(3))) void*)l, 16, 0, 0);
}

// Swizzled [rows][32] bf16 LDS tile (fallback pv staging).
__device__ __forceinline__ int swz_byte(int row, int logical_chunk) {
  return row * 64 + ((logical_chunk ^ ((row >> 1) & 3)) << 4);
}

// Fragment-major X layouts:
//  Xf (qkt): tile (rt=r>>4, kt=k>>5) at (rt*32+kt)*2048; hi 1KB then lo 1KB.
//    lane-in-tile = (r&15) + 16*((k>>3)&3), 16 B each. rt stride 65536 B.
//  XTf (pv B): tile (kt=k>>5, dt=d>>4) at (kt*64+dt)*1024; kt stride 65536 B.

// ---------------- K0: split X (fp32) into frag-major hi|lo bf16 ---------
__global__ __launch_bounds__(256) void k_split(const float* __restrict__ X,
                                               u16* __restrict__ Xf) {
  int i = blockIdx.x * 256 + threadIdx.x;   // [0, N*D/8)
  int r = i >> 7;
  int kc = (i & 127) << 3;
  float4 x0 = *(const float4*)(X + (size_t)r * D + kc);
  float4 x1 = *(const float4*)(X + (size_t)r * D + kc + 4);
  float xs[8] = {x0.x, x0.y, x0.z, x0.w, x1.x, x1.y, x1.z, x1.w};
  u16 h[8], lo[8];
#pragma unroll
  for (int j = 0; j < 8; ++j) {
    h[j] = f2bf(xs[j]);
    lo[j] = f2bf(xs[j] - bf2f(h[j]));
  }
  size_t fb = (size_t)((r >> 4) * 32 + (kc >> 5)) * 2048;
  int lbyte = ((r & 15) + ((kc >> 3) & 3) * 16) * 16;
  *(int4*)((char*)Xf + fb + lbyte) = *(int4*)h;
  *(int4*)((char*)Xf + fb + 1024 + lbyte) = *(int4*)lo;
}

// ------ K0b: X (fp32) -> XTf frag-major (FRAG=1) or XT row-major (0) ----
template <int FRAG>
__global__ __launch_bounds__(256) void k_xt(const float* __restrict__ X,
                                            u16* __restrict__ XT) {
  __shared__ u16 t[32][33];
  const int jt = blockIdx.y * 32, dt = blockIdx.x * 32;
  const int c = threadIdx.x & 31, rg = threadIdx.x >> 5;   // rg in 0..7
#pragma unroll
  for (int k = 0; k < 4; ++k) {
    int r = rg * 4 + k;
    t[r][c] = f2bf(X[(size_t)(jt + r) * D + dt + c]);
  }
  __syncthreads();
  if (FRAG) {
    if (threadIdx.x < 128) {
      int dg = dt + (threadIdx.x & 31);
      int jg = jt + (threadIdx.x >> 5) * 8;
      u16 v[8];
#pragma unroll
      for (int e = 0; e < 8; ++e) v[e] = t[(threadIdx.x >> 5) * 8 + e][threadIdx.x & 31];
      size_t tile = (size_t)(jg >> 5) * 64 + (dg >> 4);
      int lane16 = (dg & 15) + 16 * ((jg >> 3) & 3);
      *(int4*)((char*)XT + (tile << 10) + lane16 * 16) = *(int4*)v;
    }
  } else {
#pragma unroll
    for (int k = 0; k < 4; ++k) {
      int d = rg * 4 + k;
      XT[(size_t)(dt + d) * N + jt + c] = t[c][d];
    }
  }
}

// ------- K1: S = X X^T, symmetric upper-tri 128x128 blocks --------------
// Frag-direct global->VGPR with ASM-PINNED 2-deep register pipeline.
__global__ __launch_bounds__(256) void k_qkt(const u16* __restrict__ Xf,
                                             float* __restrict__ S) {
  __shared__ float tbuf[128][64];   // epilogue transpose bounce only (32 KiB)
  const int tid = threadIdx.x, wid = tid >> 6, lane = tid & 63;

  // XCD chunk swizzle over 2080 blocks (2080 = 8 * 260, bijective)
  int o = blockIdx.x;
  int l = (o & 7) * 260 + (o >> 3);
  int t = l, bi = 0;
  while (t >= 64 - bi) { t -= 64 - bi; ++bi; }
  const int bj = bi + t;
  const int brow = bi * 128, bcol = bj * 128;

  const int wr = wid >> 1, wc = wid & 1;
  const int fr = lane & 15;

  const char* Xfc = (const char*)Xf;
  const char* pA = Xfc + (size_t)(brow / 16 + wr * 4) * 65536 + lane * 16;
  const char* pB = Xfc + (size_t)(bcol / 16 + wc * 4) * 65536 + lane * 16;

  f32x4 acc[4][4] = {};

#define LOADF(P, kt) do {                                                  \
    _Pragma("unroll")                                                      \
    for (int m = 0; m < 4; ++m) {                                          \
      ALOAD2(P##ah[m], P##al[m], pA + (size_t)m * 65536 + (size_t)(kt) * 2048); \
      ALOAD2(P##bh[m], P##bl[m], pB + (size_t)m * 65536 + (size_t)(kt) * 2048); \
    }                                                                      \
  } while (0)

#define FMAF(P) do {                                                       \
    PRIO(1);                                                               \
    _Pragma("unroll")                                                      \
    for (int m = 0; m < 4; ++m)                                            \
      _Pragma("unroll")                                                    \
      for (int n = 0; n < 4; ++n) {                                        \
        acc[m][n] = __builtin_amdgcn_mfma_f32_16x16x32_bf16(P##ah[m], P##bh[n], acc[m][n], 0, 0, 0); \
        acc[m][n] = __builtin_amdgcn_mfma_f32_16x16x32_bf16(P##ah[m], P##bl[n], acc[m][n], 0, 0, 0); \
        acc[m][n] = __builtin_amdgcn_mfma_f32_16x16x32_bf16(P##al[m], P##bh[n], acc[m][n], 0, 0, 0); \
      }                                                                    \
    PRIO(0);                                                               \
  } while (0)

  bf16x8 Aah[4], Aal[4], Abh[4], Abl[4];   // buffer A (asm-pinned)
  bf16x8 Bah[4], Bal[4], Bbh[4], Bbl[4];   // buffer B (asm-pinned)

  LOADF(A, 0);                     // 16 loads outstanding
  for (int kt = 0; kt < 30; kt += 2) {
    LOADF(B, kt + 1);              // 32 outstanding
    WAITV(16);                     // buffer-A loads complete
    SB();                          // rule #18: fence MFMA below the wait
    FMAF(A);
    LOADF(A, kt + 2);
    WAITV(16);                     // buffer-B loads complete
    SB();
    FMAF(B);
  }
  LOADF(B, 31);
  WAITV(16);
  SB();
  FMAF(A);                         // tile 30
  WAITV(0);
  SB();
  FMAF(B);                         // tile 31

#undef LOADF
#undef FMAF

  const int rr = (lane >> 4) * 4;
  // direct tile write: S[brow..][bcol..]
#pragma unroll
  for (int m = 0; m < 4; ++m)
#pragma unroll
    for (int n = 0; n < 4; ++n)
#pragma unroll
      for (int r = 0; r < 4; ++r) {
        int row = brow + wr * 64 + m * 16 + rr + r;
        int col = bcol + wc * 64 + n * 16 + fr;
        S[(size_t)row * N + col] = acc[m][n][r];
      }

  // transposed tile write for off-diagonal blocks: S[bcol..][brow..]
  if (bi != bj) {
#pragma unroll
    for (int pass = 0; pass < 2; ++pass) {
      __syncthreads();
      if (wr == pass) {
#pragma unroll
        for (int m = 0; m < 4; ++m)
#pragma unroll
          for (int n = 0; n < 4; ++n) {
            f32x4 v = acc[m][n];
            int c = wc * 64 + n * 16 + fr;
            int inner = ((m * 16 + rr) * 4) ^ ((c & 15) << 4);
            *(f32x4*)((char*)&tbuf[c][0] + inner) = v;
          }
      }
      __syncthreads();
#pragma unroll
      for (int i = 0; i < 8; ++i) {
        int idx = i * 256 + tid;         // 2048 float4 = 128 cols x 16 quads
        int c = idx >> 4;
        int kq = idx & 15;
        int inner = (kq * 16) ^ ((c & 15) << 4);
        float4 v4 = *(const float4*)((const char*)&tbuf[c][0] + inner);
        *(float4*)&S[(size_t)(bcol + c) * N + brow + pass * 64 + kq * 4] = v4;
      }
    }
  }
}

// ---------------- K2: in-place row softmax (+ optional bf16 P copy) -----
template <int WRITE_PB>
__global__ __launch_bounds__(256) void k_softmax(float* __restrict__ S,
                                                 u16* __restrict__ Pb) {
  const int row = blockIdx.x;
  float* p = S + (size_t)row * N;
  const int tid = threadIdx.x;
  const int wid = tid >> 6, lane = tid & 63;
  __shared__ float red[4];

  float4 v[8];
  float m = -INFINITY;
#pragma unroll
  for (int i = 0; i < 8; ++i) {
    int idx = i * 256 + tid;
    float4 x = ((const float4*)p)[idx];
    if ((row >> 2) == idx) ((float*)&x)[row & 3] = -INFINITY;
    v[i] = x;
    m = fmaxf(m, fmaxf(fmaxf(x.x, x.y), fmaxf(x.z, x.w)));
  }
#pragma unroll
  for (int off = 32; off > 0; off >>= 1) m = fmaxf(m, __shfl_xor(m, off));
  if (lane == 0) red[wid] = m;
  __syncthreads();
  m = fmaxf(fmaxf(red[0], red[1]), fmaxf(red[2], red[3]));

  float s = 0.f;
#pragma unroll
  for (int i = 0; i < 8; ++i) {
    float4 e;
    e.x = __expf(v[i].x - m);
    e.y = __expf(v[i].y - m);
    e.z = __expf(v[i].z - m);
    e.w = __expf(v[i].w - m);
    v[i] = e;
    s += e.x + e.y + e.z + e.w;
  }
#pragma unroll
  for (int off = 32; off > 0; off >>= 1) s += __shfl_xor(s, off);
  __syncthreads();
  if (lane == 0) red[wid] = s;
  __syncthreads();
  s = red[0] + red[1] + red[2] + red[3];
  float inv = 1.0f / s;
#pragma unroll
  for (int i = 0; i < 8; ++i) {
    int idx = i * 256 + tid;
    float4 x = v[i];
    x.x *= inv; x.y *= inv; x.z *= inv; x.w *= inv;
    ((float4*)p)[idx] = x;
    if (WRITE_PB) {
      ushort4 h = {f2bf(x.x), f2bf(x.y), f2bf(x.z), f2bf(x.w)};
      ((ushort4*)(Pb + (size_t)row * N))[idx] = h;
    }
  }
}

// -------- K3: out = P @ X, frag-direct both operands, NO LDS/barriers ---
// A gathered from row-major Pb (16 rows x 64B lines per load, bytes fully
// used); B from XTf contiguous. ASM-pinned 2-deep register pipeline.
__global__ __launch_bounds__(256) void k_pv(const u16* __restrict__ Pb,
                                            const u16* __restrict__ XTf,
                                            float* __restrict__ Out) {
  const int tid = threadIdx.x, wid = tid >> 6, lane = tid & 63;

  // XCD chunk swizzle over 512 blocks (q=64, bijective)
  int o = blockIdx.x;
  int l = (o & 7) * 64 + (o >> 3);
  const int brow = (l >> 3) * 128;
  const int bcol = (l & 7) * 128;

  const int wr = wid >> 1, wc = wid & 1;   // 2x2 waves, 64x64 each
  const int fr = lane & 15;

  // A: row-major Pb gather base (per-lane row + k-chunk)
  const u16* paw = Pb + (size_t)(brow + wr * 64 + (lane & 15)) * N + (lane >> 4) * 8;
  // B: frag-major XTf base
  const char* pbw = (const char*)XTf + (size_t)(bcol / 16 + wc * 4) * 1024 + lane * 16;

  f32x4 acc[4][4] = {};

#define LOADPV(P, kt) do {                                                 \
    _Pragma("unroll")                                                      \
    for (int m = 0; m < 4; ++m)                                            \
      ALOAD(P##a[m], paw + (size_t)m * (16 * N) + (size_t)(kt) * 32);      \
    _Pragma("unroll")                                                      \
    for (int n = 0; n < 4; ++n)                                            \
      ALOAD(P##b[n], pbw + (size_t)n * 1024 + (size_t)(kt) * 65536);       \
  } while (0)

#define FMAPV(P) do {                                                      \
    PRIO(1);                                                               \
    _Pragma("unroll")                                                      \
    for (int m = 0; m < 4; ++m)                                            \
      _Pragma("unroll")                                                    \
      for (int n = 0; n < 4; ++n)                                          \
        acc[m][n] = __builtin_amdgcn_mfma_f32_16x16x32_bf16(P##a[m], P##b[n], acc[m][n], 0, 0, 0); \
    PRIO(0);                                                               \
  } while (0)

  bf16x8 Aa[4], Ab[4];   // buffer A (asm-pinned)
  bf16x8 Ba[4], Bb[4];   // buffer B (asm-pinned)

  LOADPV(A, 0);                    // 8 loads outstanding
  for (int it = 0; it < 254; it += 2) {
    LOADPV(B, it + 1);             // 16 outstanding
    WAITV(8);
    SB();
    FMAPV(A);
    LOADPV(A, it + 2);
    WAITV(8);
    SB();
    FMAPV(B);
  }
  LOADPV(B, 255);
  WAITV(8);
  SB();
  FMAPV(A);                        // tile 254
  WAITV(0);
  SB();
  FMAPV(B);                        // tile 255

#undef LOADPV
#undef FMAPV

  const int rr = (lane >> 4) * 4;
#pragma unroll
  for (int m = 0; m < 4; ++m)
#pragma unroll
    for (int n = 0; n < 4; ++n)
#pragma unroll
      for (int r = 0; r < 4; ++r) {
        int row = brow + wr * 64 + m * 16 + rr + r;
        int col = bcol + wc * 64 + n * 16 + fr;
        Out[(size_t)row * D + col] = acc[m][n][r];
      }
}

// -------- K3 fallback: out = P @ X from fp32 P (row-major XT) -----------
__global__ __launch_bounds__(512) void k_pv_f32(const float* __restrict__ P,
                                                const u16* __restrict__ XT,
                                                float* __restrict__ Out) {
  __shared__ u16 As[128 * 32];
  __shared__ u16 Bs[256 * 32];
  const int tid = threadIdx.x, wid = tid >> 6, lane = tid & 63;
  const int brow = blockIdx.y * 128;
  const int bcol = blockIdx.x * 256;
  const int wr = wid >> 2, wc = wid & 3;
  const int fr = lane & 15;
  const int c0 = lane >> 4;

  f32x4 acc[4][4] = {};

  for (int kt = 0; kt < N; kt += 32) {
    __syncthreads();
#pragma unroll
    for (int c = 0; c < 2; ++c) {
      int chunk = wid * 2 + c;
      int ebyte = chunk * 1024 + lane * 16;
      int row = ebyte >> 6;
      int pc = (ebyte >> 4) & 3;
      int col = (pc ^ ((row >> 1) & 3)) * 8;
      gload_lds16(XT + (size_t)(bcol + row) * N + kt + col, (const char*)Bs + ebyte);
    }
#pragma unroll
    for (int i = 0; i < 2; ++i) {
      int idx = i * 512 + tid;
      int e = idx * 4;
      int row = e >> 5, col = e & 31;
      float4 x = *(const float4*)(P + (size_t)(brow + row) * N + kt + col);
      ushort4 h = {f2bf(x.x), f2bf(x.y), f2bf(x.z), f2bf(x.w)};
      int inner = (col * 2) ^ (((row >> 1) & 3) << 4);
      *(ushort4*)((char*)As + row * 64 + inner) = h;
    }
    __syncthreads();

    bf16x8 a[4], b[4];
#pragma unroll
    for (int m = 0; m < 4; ++m) {
      int row = wr * 64 + m * 16 + fr;
      a[m] = *(const bf16x8*)((const char*)As + swz_byte(row, c0));
    }
#pragma unroll
    for (int n = 0; n < 4; ++n) {
      int row = wc * 64 + n * 16 + fr;
      b[n] = *(const bf16x8*)((const char*)Bs + swz_byte(row, c0));
    }
#pragma unroll
    for (int m = 0; m < 4; ++m)
#pragma unroll
      for (int n = 0; n < 4; ++n)
        acc[m][n] = __builtin_amdgcn_mfma_f32_16x16x32_bf16(a[m], b[n], acc[m][n], 0, 0, 0);
  }

  const int rr = (lane >> 4) * 4;
#pragma unroll
  for (int m = 0; m < 4; ++m)
#pragma unroll
    for (int n = 0; n < 4; ++n)
#pragma unroll
      for (int r = 0; r < 4; ++r) {
        int row = brow + wr * 64 + m * 16 + rr + r;
        int col = bcol + wc * 64 + n * 16 + fr;
        Out[(size_t)row * D + col] = acc[m][n][r];
      }
}

extern "C" void kernel_launch(void* const* d_in, const int* in_sizes, int n_in,
                              void* d_out, int out_size, void* d_ws, size_t ws_size,
                              hipStream_t stream) {
  const float* X = (const float*)d_in[0];
  float* out = (float*)d_out;
  float* attn = out + (size_t)N * D;        // second output: raw S, then softmaxed

  u16* Xf = (u16*)d_ws;                     // 32 MB (frag-major hi|lo)
  u16* XT = Xf + (size_t)2 * N * D;         // 16 MB (XTf frag-major, or row-major)
  u16* Pb = XT + (size_t)N * D;             // 128 MB (optional)
  const bool usePb =
      ws_size >= ((size_t)N * D * 3 + (size_t)N * N) * sizeof(u16);

  k_split<<<(N * D / 8) / 256, 256, 0, stream>>>(X, Xf);
  k_qkt<<<64 * 65 / 2, 256, 0, stream>>>(Xf, attn);
  if (usePb) {
    k_xt<1><<<dim3(D / 32, N / 32), 256, 0, stream>>>(X, XT);
    k_softmax<1><<<N, 256, 0, stream>>>(attn, Pb);
    k_pv<<<512, 256, 0, stream>>>(Pb, XT, out);
  } else {
    k_xt<0><<<dim3(D / 32, N / 32), 256, 0, stream>>>(X, XT);
    k_softmax<0><<<N, 256, 0, stream>>>(attn, nullptr);
    k_pv_f32<<<dim3(D / 256, N / 128), 512, 0, stream>>>(attn, XT, out);
  }
}

// Round 11
// 633.110 us; speedup vs baseline: 1.1073x; 1.1073x over previous
//
#include <hip/hip_runtime.h>

#define N 8192
#define D 1024

typedef short bf16x8 __attribute__((ext_vector_type(8)));
typedef float f32x4 __attribute__((ext_vector_type(4)));
typedef unsigned short u16;

#define WAITV(n) asm volatile("s_waitcnt vmcnt(" #n ")" ::: "memory")
#define BAR() __builtin_amdgcn_s_barrier()
#define SB() __builtin_amdgcn_sched_barrier(0)
#define PRIO(p) __builtin_amdgcn_s_setprio(p)

__device__ __forceinline__ u16 f2bf(float f) {
  unsigned u = __float_as_uint(f);
  u += 0x7FFF + ((u >> 16) & 1);   // RNE to bf16
  return (u16)(u >> 16);
}
__device__ __forceinline__ float bf2f(u16 h) {
  return __uint_as_float(((unsigned)h) << 16);
}

__device__ __forceinline__ void gload_lds16(const void* g, const void* l) {
  __builtin_amdgcn_global_load_lds(
      (const __attribute__((address_space(1))) void*)g,
      (__attribute__((address_space(3))) void*)l, 16, 0, 0);
}

// Swizzled [rows][32] bf16 LDS tile (pv A-staging): 64 B/row, 4x16B chunks.
__device__ __forceinline__ int swz_byte(int row, int logical_chunk) {
  return row * 64 + ((logical_chunk ^ ((row >> 1) & 3)) << 4);
}

// Fragment-major X layouts:
//  Xf (qkt): tile (rt=r>>4, kt=k>>5) at (rt*32+kt)*2048; hi 1KB then lo 1KB.
//    lane-in-tile = (r&15) + 16*((k>>3)&3), 16 B each. rt stride 65536 B.
//  XTf (pv B): tile (kt=k>>5, dt=d>>4) at (kt*64+dt)*1024; kt stride 65536 B.

// ---------------- K0: split X (fp32) into frag-major hi|lo bf16 ---------
__global__ __launch_bounds__(256) void k_split(const float* __restrict__ X,
                                               u16* __restrict__ Xf) {
  int i = blockIdx.x * 256 + threadIdx.x;   // [0, N*D/8)
  int r = i >> 7;
  int kc = (i & 127) << 3;
  float4 x0 = *(const float4*)(X + (size_t)r * D + kc);
  float4 x1 = *(const float4*)(X + (size_t)r * D + kc + 4);
  float xs[8] = {x0.x, x0.y, x0.z, x0.w, x1.x, x1.y, x1.z, x1.w};
  u16 h[8], lo[8];
#pragma unroll
  for (int j = 0; j < 8; ++j) {
    h[j] = f2bf(xs[j]);
    lo[j] = f2bf(xs[j] - bf2f(h[j]));
  }
  size_t fb = (size_t)((r >> 4) * 32 + (kc >> 5)) * 2048;
  int lbyte = ((r & 15) + ((kc >> 3) & 3) * 16) * 16;
  *(int4*)((char*)Xf + fb + lbyte) = *(int4*)h;
  *(int4*)((char*)Xf + fb + 1024 + lbyte) = *(int4*)lo;
}

// ------ K0b: X (fp32) -> XTf frag-major (FRAG=1) or XT row-major (0) ----
template <int FRAG>
__global__ __launch_bounds__(256) void k_xt(const float* __restrict__ X,
                                            u16* __restrict__ XT) {
  __shared__ u16 t[32][33];
  const int jt = blockIdx.y * 32, dt = blockIdx.x * 32;
  const int c = threadIdx.x & 31, rg = threadIdx.x >> 5;   // rg in 0..7
#pragma unroll
  for (int k = 0; k < 4; ++k) {
    int r = rg * 4 + k;
    t[r][c] = f2bf(X[(size_t)(jt + r) * D + dt + c]);
  }
  __syncthreads();
  if (FRAG) {
    if (threadIdx.x < 128) {
      int dg = dt + (threadIdx.x & 31);
      int jg = jt + (threadIdx.x >> 5) * 8;
      u16 v[8];
#pragma unroll
      for (int e = 0; e < 8; ++e) v[e] = t[(threadIdx.x >> 5) * 8 + e][threadIdx.x & 31];
      size_t tile = (size_t)(jg >> 5) * 64 + (dg >> 4);
      int lane16 = (dg & 15) + 16 * ((jg >> 3) & 3);
      *(int4*)((char*)XT + (tile << 10) + lane16 * 16) = *(int4*)v;
    }
  } else {
#pragma unroll
    for (int k = 0; k < 4; ++k) {
      int d = rg * 4 + k;
      XT[(size_t)(dt + d) * N + jt + c] = t[c][d];
    }
  }
}

// ------- K1: S = X X^T, symmetric upper-tri 256x256 blocks, 8 waves -----
// All-LDS frag-major staging (1 KB contiguous chunks: conflict-free DMA
// writes AND frag reads). Serialized stage->sync->compute (R4/R6 lesson).
// Wave tile 128x64 -> 96 MFMA per kt per wave (high intensity).
__global__ __launch_bounds__(512, 2) void k_qkt(const u16* __restrict__ Xf,
                                                float* __restrict__ S) {
  __shared__ union {
    u16 ab[2][16384];      // [0]=A (16 rt x 2KB hi|lo), [1]=B; 64 KiB total
    float tbuf[32][256];   // epilogue transpose bounce (32 KiB)
  } sm;
  const int tid = threadIdx.x, wid = tid >> 6, lane = tid & 63;

  // XCD chunk swizzle over 528 blocks (528 = 8 * 66, bijective)
  int o = blockIdx.x;
  int l = (o & 7) * 66 + (o >> 3);
  int t = l, bi = 0;
  while (t >= 32 - bi) { t -= 32 - bi; ++bi; }
  const int bj = bi + t;
  const int brow = bi * 256, bcol = bj * 256;

  const int wr = wid >> 2, wc = wid & 3;   // 2x4 waves; wave tile 128x64
  const int fr = lane & 15;
  const int chunk0 = wid * 8;              // this wave's 8 staging chunks

  const char* Xfc = (const char*)Xf;

  f32x4 acc[8][4] = {};

  for (int kt = 0; kt < 32; ++kt) {
    __syncthreads();                 // prior compute's LDS reads done
    // stage A (32 KB) + B (32 KB): 64 x 1KB chunks, 8 per wave
#pragma unroll
    for (int c = 0; c < 8; ++c) {
      int chunk = chunk0 + c;        // 0..63
      int idx = chunk & 31;
      int rt = idx >> 1;             // 0..15
      int hl = idx & 1;              // 0=hi, 1=lo
      int rbase = (chunk >= 32) ? bcol : brow;
      const char* src = Xfc + (size_t)(rbase / 16 + rt) * 65536 +
                        (size_t)kt * 2048 + hl * 1024 + lane * 16;
      gload_lds16(src, (const char*)sm.ab[0] + chunk * 1024 + lane * 16);
    }
    WAITV(0);
    __syncthreads();                 // all 64 KB staged

    bf16x8 bh[4], bl[4];
#pragma unroll
    for (int n = 0; n < 4; ++n) {
      const char* bp = (const char*)sm.ab[1] + (wc * 4 + n) * 2048 + lane * 16;
      bh[n] = *(const bf16x8*)bp;
      bl[n] = *(const bf16x8*)(bp + 1024);
    }
    PRIO(1);
#pragma unroll
    for (int m = 0; m < 8; ++m) {
      const char* ap = (const char*)sm.ab[0] + (wr * 8 + m) * 2048 + lane * 16;
      bf16x8 ah = *(const bf16x8*)ap;
      bf16x8 al = *(const bf16x8*)(ap + 1024);
#pragma unroll
      for (int n = 0; n < 4; ++n) {
        acc[m][n] = __builtin_amdgcn_mfma_f32_16x16x32_bf16(ah, bh[n], acc[m][n], 0, 0, 0);
        acc[m][n] = __builtin_amdgcn_mfma_f32_16x16x32_bf16(ah, bl[n], acc[m][n], 0, 0, 0);
        acc[m][n] = __builtin_amdgcn_mfma_f32_16x16x32_bf16(al, bh[n], acc[m][n], 0, 0, 0);
      }
    }
    PRIO(0);
  }

  const int rr = (lane >> 4) * 4;
  // direct tile write: S[brow..][bcol..]
#pragma unroll
  for (int m = 0; m < 8; ++m)
#pragma unroll
    for (int n = 0; n < 4; ++n)
#pragma unroll
      for (int r = 0; r < 4; ++r) {
        int row = brow + wr * 128 + m * 16 + rr + r;
        int col = bcol + wc * 64 + n * 16 + fr;
        S[(size_t)row * N + col] = acc[m][n][r];
      }

  // transposed tile write for off-diagonal blocks: S[bcol..][brow..]
  // 8 passes of 32 cols x 256 rows, XOR-swizzled tbuf (R5-proven pattern).
  if (bi != bj) {
#pragma unroll
    for (int p = 0; p < 8; ++p) {
      __syncthreads();               // ab/tbuf reuse + prior reads done
      if (wc == (p >> 1)) {          // 2 writer waves (wr = 0,1)
#pragma unroll
        for (int m = 0; m < 8; ++m)
#pragma unroll
          for (int nn = 0; nn < 2; ++nn) {
            int n = (p & 1) * 2 + nn;
            f32x4 v = acc[m][n];
            int c = nn * 16 + fr;                 // 0..31 col-in-pass
            int rl = wr * 128 + m * 16 + rr;      // 0..252 row-quad base
            int inner = (rl * 4) ^ ((c & 15) << 4);
            *(f32x4*)((char*)&sm.tbuf[c][0] + inner) = v;
          }
      }
      __syncthreads();
#pragma unroll
      for (int i = 0; i < 4; ++i) {
        int idx = i * 512 + tid;     // 2048 float4 = 32 cols x 64 quads
        int c = idx >> 6;            // 0..31
        int q = idx & 63;            // row quad
        int inner = (q * 16) ^ ((c & 15) << 4);
        float4 v4 = *(const float4*)((const char*)&sm.tbuf[c][0] + inner);
        *(float4*)&S[(size_t)(bcol + p * 32 + c) * N + brow + q * 4] = v4;
      }
    }
  }
}

// ---------------- K2: in-place row softmax (+ optional bf16 P copy) -----
template <int WRITE_PB>
__global__ __launch_bounds__(256) void k_softmax(float* __restrict__ S,
                                                 u16* __restrict__ Pb) {
  const int row = blockIdx.x;
  float* p = S + (size_t)row * N;
  const int tid = threadIdx.x;
  const int wid = tid >> 6, lane = tid & 63;
  __shared__ float red[4];

  float4 v[8];
  float m = -INFINITY;
#pragma unroll
  for (int i = 0; i < 8; ++i) {
    int idx = i * 256 + tid;
    float4 x = ((const float4*)p)[idx];
    if ((row >> 2) == idx) ((float*)&x)[row & 3] = -INFINITY;
    v[i] = x;
    m = fmaxf(m, fmaxf(fmaxf(x.x, x.y), fmaxf(x.z, x.w)));
  }
#pragma unroll
  for (int off = 32; off > 0; off >>= 1) m = fmaxf(m, __shfl_xor(m, off));
  if (lane == 0) red[wid] = m;
  __syncthreads();
  m = fmaxf(fmaxf(red[0], red[1]), fmaxf(red[2], red[3]));

  float s = 0.f;
#pragma unroll
  for (int i = 0; i < 8; ++i) {
    float4 e;
    e.x = __expf(v[i].x - m);
    e.y = __expf(v[i].y - m);
    e.z = __expf(v[i].z - m);
    e.w = __expf(v[i].w - m);
    v[i] = e;
    s += e.x + e.y + e.z + e.w;
  }
#pragma unroll
  for (int off = 32; off > 0; off >>= 1) s += __shfl_xor(s, off);
  __syncthreads();
  if (lane == 0) red[wid] = s;
  __syncthreads();
  s = red[0] + red[1] + red[2] + red[3];
  float inv = 1.0f / s;
#pragma unroll
  for (int i = 0; i < 8; ++i) {
    int idx = i * 256 + tid;
    float4 x = v[i];
    x.x *= inv; x.y *= inv; x.z *= inv; x.w *= inv;
    ((float4*)p)[idx] = x;
    if (WRITE_PB) {
      ushort4 h = {f2bf(x.x), f2bf(x.y), f2bf(x.z), f2bf(x.w)};
      ((ushort4*)(Pb + (size_t)row * N))[idx] = h;
    }
  }
}

// -------- K3: out = P @ X. A: Pb via gload_lds (3-deep/4-slot); ---------
// B: frag-direct from XTf (2-deep reg buffers). Mixed-stream counted vmcnt.
// (R9-proven structure, best measured pv.)
__global__ __launch_bounds__(256) void k_pv(const u16* __restrict__ Pb,
                                            const u16* __restrict__ XTf,
                                            float* __restrict__ Out) {
  __shared__ u16 As[4][128 * 32];   // 32 KiB
  const int tid = threadIdx.x, wid = tid >> 6, lane = tid & 63;

  // XCD chunk swizzle over 512 blocks (q=64, bijective)
  int o = blockIdx.x;
  int l = (o & 7) * 64 + (o >> 3);
  const int brow = (l >> 3) * 128;
  const int bcol = (l & 7) * 128;

  const int wr = wid >> 1, wc = wid & 1;   // 2x2 waves, 64x64 each
  const int fr = lane & 15;
  const int c0 = lane >> 4;

  const char* pB = (const char*)XTf + (size_t)(bcol / 16 + wc * 4) * 1024 + lane * 16;

  f32x4 acc[4][4] = {};

#define STAGEA(t) do {                                                     \
    _Pragma("unroll")                                                      \
    for (int c = 0; c < 2; ++c) {                                          \
      int chunk = wid * 2 + c;                                             \
      int ebyte = chunk * 1024 + lane * 16;                                \
      int row = ebyte >> 6;                                                \
      int pc = (ebyte >> 4) & 3;                                           \
      int col = (pc ^ ((row >> 1) & 3)) * 8;                               \
      gload_lds16(Pb + (size_t)(brow + row) * N + (t) * 32 + col,          \
                  (const char*)As[(t) & 3] + ebyte);                       \
    }                                                                      \
  } while (0)

#define LOADB(BUF, t) do {                                                 \
    const char* b_ = pB + ((size_t)(t) << 16);                             \
    BUF[0] = *(const bf16x8*)(b_);                                         \
    BUF[1] = *(const bf16x8*)(b_ + 1024);                                  \
    BUF[2] = *(const bf16x8*)(b_ + 2048);                                  \
    BUF[3] = *(const bf16x8*)(b_ + 3072);                                  \
  } while (0)

#define PV_COMPUTE(s, BUF) do {                                            \
    bf16x8 a[4];                                                           \
    _Pragma("unroll")                                                      \
    for (int m = 0; m < 4; ++m) {                                          \
      int row = wr * 64 + m * 16 + fr;                                     \
      a[m] = *(const bf16x8*)((const char*)As[s] + swz_byte(row, c0));     \
    }                                                                      \
    PRIO(1);                                                               \
    _Pragma("unroll")                                                      \
    for (int m = 0; m < 4; ++m)                                            \
      _Pragma("unroll")                                                    \
      for (int n = 0; n < 4; ++n)                                          \
        acc[m][n] = __builtin_amdgcn_mfma_f32_16x16x32_bf16(a[m], BUF[n], acc[m][n], 0, 0, 0); \
    PRIO(0);                                                               \
  } while (0)

  bf16x8 B0[4], B1[4];

  STAGEA(0); STAGEA(1); STAGEA(2);   // 6 vmem ops
  LOADB(B0, 0);                      // 4 vmem ops
  SB();

  for (int it = 0; it < 254; it += 2) {
    LOADB(B1, it + 1);
    STAGEA(it + 3);
    SB();
    WAITV(6);
    BAR();
    PV_COMPUTE(it & 3, B0);
    BAR();
    LOADB(B0, it + 2);
    if (it + 4 < 256) STAGEA(it + 4);
    SB();
    WAITV(6);
    BAR();
    PV_COMPUTE((it + 1) & 3, B1);
    BAR();
  }
  // tail: tiles 254, 255 (in flight: A(255) [2], B0<-254 [4])
  LOADB(B1, 255);
  SB();
  WAITV(4);
  BAR();
  PV_COMPUTE(2, B0);
  BAR();
  WAITV(0);
  PV_COMPUTE(3, B1);

#undef STAGEA
#undef LOADB
#undef PV_COMPUTE

  const int rr = (lane >> 4) * 4;
#pragma unroll
  for (int m = 0; m < 4; ++m)
#pragma unroll
    for (int n = 0; n < 4; ++n)
#pragma unroll
      for (int r = 0; r < 4; ++r) {
        int row = brow + wr * 64 + m * 16 + rr + r;
        int col = bcol + wc * 64 + n * 16 + fr;
        Out[(size_t)row * D + col] = acc[m][n][r];
      }
}

// -------- K3 fallback: out = P @ X from fp32 P (row-major XT) -----------
__global__ __launch_bounds__(512) void k_pv_f32(const float* __restrict__ P,
                                                const u16* __restrict__ XT,
                                                float* __restrict__ Out) {
  __shared__ u16 As[128 * 32];
  __shared__ u16 Bs[256 * 32];
  const int tid = threadIdx.x, wid = tid >> 6, lane = tid & 63;
  const int brow = blockIdx.y * 128;
  const int bcol = blockIdx.x * 256;
  const int wr = wid >> 2, wc = wid & 3;
  const int fr = lane & 15;
  const int c0 = lane >> 4;

  f32x4 acc[4][4] = {};

  for (int kt = 0; kt < N; kt += 32) {
    __syncthreads();
#pragma unroll
    for (int c = 0; c < 2; ++c) {
      int chunk = wid * 2 + c;
      int ebyte = chunk * 1024 + lane * 16;
      int row = ebyte >> 6;
      int pc = (ebyte >> 4) & 3;
      int col = (pc ^ ((row >> 1) & 3)) * 8;
      gload_lds16(XT + (size_t)(bcol + row) * N + kt + col, (const char*)Bs + ebyte);
    }
#pragma unroll
    for (int i = 0; i < 2; ++i) {
      int idx = i * 512 + tid;
      int e = idx * 4;
      int row = e >> 5, col = e & 31;
      float4 x = *(const float4*)(P + (size_t)(brow + row) * N + kt + col);
      ushort4 h = {f2bf(x.x), f2bf(x.y), f2bf(x.z), f2bf(x.w)};
      int inner = (col * 2) ^ (((row >> 1) & 3) << 4);
      *(ushort4*)((char*)As + row * 64 + inner) = h;
    }
    __syncthreads();

    bf16x8 a[4], b[4];
#pragma unroll
    for (int m = 0; m < 4; ++m) {
      int row = wr * 64 + m * 16 + fr;
      a[m] = *(const bf16x8*)((const char*)As + swz_byte(row, c0));
    }
#pragma unroll
    for (int n = 0; n < 4; ++n) {
      int row = wc * 64 + n * 16 + fr;
      b[n] = *(const bf16x8*)((const char*)Bs + swz_byte(row, c0));
    }
#pragma unroll
    for (int m = 0; m < 4; ++m)
#pragma unroll
      for (int n = 0; n < 4; ++n)
        acc[m][n] = __builtin_amdgcn_mfma_f32_16x16x32_bf16(a[m], b[n], acc[m][n], 0, 0, 0);
  }

  const int rr = (lane >> 4) * 4;
#pragma unroll
  for (int m = 0; m < 4; ++m)
#pragma unroll
    for (int n = 0; n < 4; ++n)
#pragma unroll
      for (int r = 0; r < 4; ++r) {
        int row = brow + wr * 64 + m * 16 + rr + r;
        int col = bcol + wc * 64 + n * 16 + fr;
        Out[(size_t)row * D + col] = acc[m][n][r];
      }
}

extern "C" void kernel_launch(void* const* d_in, const int* in_sizes, int n_in,
                              void* d_out, int out_size, void* d_ws, size_t ws_size,
                              hipStream_t stream) {
  const float* X = (const float*)d_in[0];
  float* out = (float*)d_out;
  float* attn = out + (size_t)N * D;        // second output: raw S, then softmaxed

  u16* Xf = (u16*)d_ws;                     // 32 MB (frag-major hi|lo)
  u16* XT = Xf + (size_t)2 * N * D;         // 16 MB (XTf frag-major, or row-major)
  u16* Pb = XT + (size_t)N * D;             // 128 MB (optional)
  const bool usePb =
      ws_size >= ((size_t)N * D * 3 + (size_t)N * N) * sizeof(u16);

  k_split<<<(N * D / 8) / 256, 256, 0, stream>>>(X, Xf);
  k_qkt<<<32 * 33 / 2, 512, 0, stream>>>(Xf, attn);
  if (usePb) {
    k_xt<1><<<dim3(D / 32, N / 32), 256, 0, stream>>>(X, XT);
    k_softmax<1><<<N, 256, 0, stream>>>(attn, Pb);
    k_pv<<<512, 256, 0, stream>>>(Pb, XT, out);
  } else {
    k_xt<0><<<dim3(D / 32, N / 32), 256, 0, stream>>>(X, XT);
    k_softmax<0><<<N, 256, 0, stream>>>(attn, nullptr);
    k_pv_f32<<<dim3(D / 256, N / 128), 512, 0, stream>>>(attn, XT, out);
  }
}

// Round 12
// 585.047 us; speedup vs baseline: 1.1983x; 1.0822x over previous
//
#include <hip/hip_runtime.h>

#define N 8192
#define D 1024

typedef short bf16x8 __attribute__((ext_vector_type(8)));
typedef float f32x4 __attribute__((ext_vector_type(4)));
typedef unsigned short u16;

#define WAITV(n) asm volatile("s_waitcnt vmcnt(" #n ")" ::: "memory")
#define BAR() __builtin_amdgcn_s_barrier()
#define SB() __builtin_amdgcn_sched_barrier(0)
#define PRIO(p) __builtin_amdgcn_s_setprio(p)

// Opaque asm load: compiler cannot sink it toward its consumer, so the
// 3-deep register pipeline actually materializes. vmcnt managed manually.
#define ALOAD(d, p) \
  asm volatile("global_load_dwordx4 %0, %1, off" : "=&v"(d) : "v"(p))

__device__ __forceinline__ u16 f2bf(float f) {
  unsigned u = __float_as_uint(f);
  u += 0x7FFF + ((u >> 16) & 1);   // RNE to bf16
  return (u16)(u >> 16);
}
__device__ __forceinline__ float bf2f(u16 h) {
  return __uint_as_float(((unsigned)h) << 16);
}

__device__ __forceinline__ void gload_lds16(const void* g, const void* l) {
  __builtin_amdgcn_global_load_lds(
      (const __attribute__((address_space(1))) void*)g,
      (__attribute__((address_space(3))) void*)l, 16, 0, 0);
}

// Swizzled [rows][32] bf16 LDS tile (pv A-staging): 64 B/row, 4x16B chunks.
__device__ __forceinline__ int swz_byte(int row, int logical_chunk) {
  return row * 64 + ((logical_chunk ^ ((row >> 1) & 3)) << 4);
}

// Fragment-major X layouts:
//  Xf (qkt): tile (rt=r>>4, kt=k>>5) at (rt*32+kt)*2048; hi 1KB then lo 1KB.
//    lane-in-tile = (r&15) + 16*((k>>3)&3), 16 B each. rt stride 65536 B.
//  XTf (pv B): tile (kt=k>>5, dt=d>>4) at (kt*64+dt)*1024; kt stride 65536 B.

// ---------------- K0: split X (fp32) into frag-major hi|lo bf16 ---------
__global__ __launch_bounds__(256) void k_split(const float* __restrict__ X,
                                               u16* __restrict__ Xf) {
  int i = blockIdx.x * 256 + threadIdx.x;   // [0, N*D/8)
  int r = i >> 7;
  int kc = (i & 127) << 3;
  float4 x0 = *(const float4*)(X + (size_t)r * D + kc);
  float4 x1 = *(const float4*)(X + (size_t)r * D + kc + 4);
  float xs[8] = {x0.x, x0.y, x0.z, x0.w, x1.x, x1.y, x1.z, x1.w};
  u16 h[8], lo[8];
#pragma unroll
  for (int j = 0; j < 8; ++j) {
    h[j] = f2bf(xs[j]);
    lo[j] = f2bf(xs[j] - bf2f(h[j]));
  }
  size_t fb = (size_t)((r >> 4) * 32 + (kc >> 5)) * 2048;
  int lbyte = ((r & 15) + ((kc >> 3) & 3) * 16) * 16;
  *(int4*)((char*)Xf + fb + lbyte) = *(int4*)h;
  *(int4*)((char*)Xf + fb + 1024 + lbyte) = *(int4*)lo;
}

// ------ K0b: X (fp32) -> XTf frag-major (FRAG=1) or XT row-major (0) ----
template <int FRAG>
__global__ __launch_bounds__(256) void k_xt(const float* __restrict__ X,
                                            u16* __restrict__ XT) {
  __shared__ u16 t[32][33];
  const int jt = blockIdx.y * 32, dt = blockIdx.x * 32;
  const int c = threadIdx.x & 31, rg = threadIdx.x >> 5;   // rg in 0..7
#pragma unroll
  for (int k = 0; k < 4; ++k) {
    int r = rg * 4 + k;
    t[r][c] = f2bf(X[(size_t)(jt + r) * D + dt + c]);
  }
  __syncthreads();
  if (FRAG) {
    if (threadIdx.x < 128) {
      int dg = dt + (threadIdx.x & 31);
      int jg = jt + (threadIdx.x >> 5) * 8;
      u16 v[8];
#pragma unroll
      for (int e = 0; e < 8; ++e) v[e] = t[(threadIdx.x >> 5) * 8 + e][threadIdx.x & 31];
      size_t tile = (size_t)(jg >> 5) * 64 + (dg >> 4);
      int lane16 = (dg & 15) + 16 * ((jg >> 3) & 3);
      *(int4*)((char*)XT + (tile << 10) + lane16 * 16) = *(int4*)v;
    }
  } else {
#pragma unroll
    for (int k = 0; k < 4; ++k) {
      int d = rg * 4 + k;
      XT[(size_t)(dt + d) * N + jt + c] = t[c][d];
    }
  }
}

// ------- K1: S = X X^T, symmetric upper-tri 128x128 blocks --------------
// Fragment-direct global->VGPR (R9-proven, best measured qkt: ~235 us).
__global__ __launch_bounds__(256) void k_qkt(const u16* __restrict__ Xf,
                                             float* __restrict__ S) {
  __shared__ float tbuf[128][64];   // epilogue transpose bounce only (32 KiB)
  const int tid = threadIdx.x, wid = tid >> 6, lane = tid & 63;

  // XCD chunk swizzle over 2080 blocks (2080 = 8 * 260, bijective)
  int o = blockIdx.x;
  int l = (o & 7) * 260 + (o >> 3);
  int t = l, bi = 0;
  while (t >= 64 - bi) { t -= 64 - bi; ++bi; }
  const int bj = bi + t;
  const int brow = bi * 128, bcol = bj * 128;

  const int wr = wid >> 1, wc = wid & 1;
  const int fr = lane & 15;

  const char* Xfc = (const char*)Xf;
  const char* pA = Xfc + (size_t)(brow / 16 + wr * 4) * 65536 + lane * 16;
  const char* pB = Xfc + (size_t)(bcol / 16 + wc * 4) * 65536 + lane * 16;

  f32x4 acc[4][4] = {};

#define LOADF(P, kt) do {                                                  \
    _Pragma("unroll")                                                      \
    for (int m = 0; m < 4; ++m) {                                          \
      const char* a_ = pA + (size_t)m * 65536 + (size_t)(kt) * 2048;       \
      const char* b_ = pB + (size_t)m * 65536 + (size_t)(kt) * 2048;       \
      P##ah[m] = *(const bf16x8*)a_;                                       \
      P##al[m] = *(const bf16x8*)(a_ + 1024);                              \
      P##bh[m] = *(const bf16x8*)b_;                                       \
      P##bl[m] = *(const bf16x8*)(b_ + 1024);                              \
    }                                                                      \
  } while (0)

#define FMAF(P) do {                                                       \
    PRIO(1);                                                               \
    _Pragma("unroll")                                                      \
    for (int m = 0; m < 4; ++m)                                            \
      _Pragma("unroll")                                                    \
      for (int n = 0; n < 4; ++n) {                                        \
        acc[m][n] = __builtin_amdgcn_mfma_f32_16x16x32_bf16(P##ah[m], P##bh[n], acc[m][n], 0, 0, 0); \
        acc[m][n] = __builtin_amdgcn_mfma_f32_16x16x32_bf16(P##ah[m], P##bl[n], acc[m][n], 0, 0, 0); \
        acc[m][n] = __builtin_amdgcn_mfma_f32_16x16x32_bf16(P##al[m], P##bh[n], acc[m][n], 0, 0, 0); \
      }                                                                    \
    PRIO(0);                                                               \
  } while (0)

  bf16x8 Aah[4], Aal[4], Abh[4], Abl[4];   // buffer A
  bf16x8 Bah[4], Bal[4], Bbh[4], Bbl[4];   // buffer B

  LOADF(A, 0);
  SB();
  for (int kt = 0; kt < 30; kt += 2) {
    LOADF(B, kt + 1);
    SB();
    FMAF(A);
    LOADF(A, kt + 2);
    SB();
    FMAF(B);
  }
  LOADF(B, 31);
  SB();
  FMAF(A);
  FMAF(B);

#undef LOADF
#undef FMAF

  const int rr = (lane >> 4) * 4;
  // direct tile write: S[brow..][bcol..]
#pragma unroll
  for (int m = 0; m < 4; ++m)
#pragma unroll
    for (int n = 0; n < 4; ++n)
#pragma unroll
      for (int r = 0; r < 4; ++r) {
        int row = brow + wr * 64 + m * 16 + rr + r;
        int col = bcol + wc * 64 + n * 16 + fr;
        S[(size_t)row * N + col] = acc[m][n][r];
      }

  // transposed tile write for off-diagonal blocks: S[bcol..][brow..]
  if (bi != bj) {
#pragma unroll
    for (int pass = 0; pass < 2; ++pass) {
      __syncthreads();
      if (wr == pass) {
#pragma unroll
        for (int m = 0; m < 4; ++m)
#pragma unroll
          for (int n = 0; n < 4; ++n) {
            f32x4 v = acc[m][n];
            int c = wc * 64 + n * 16 + fr;
            int inner = ((m * 16 + rr) * 4) ^ ((c & 15) << 4);
            *(f32x4*)((char*)&tbuf[c][0] + inner) = v;
          }
      }
      __syncthreads();
#pragma unroll
      for (int i = 0; i < 8; ++i) {
        int idx = i * 256 + tid;         // 2048 float4 = 128 cols x 16 quads
        int c = idx >> 4;
        int kq = idx & 15;
        int inner = (kq * 16) ^ ((c & 15) << 4);
        float4 v4 = *(const float4*)((const char*)&tbuf[c][0] + inner);
        *(float4*)&S[(size_t)(bcol + c) * N + brow + pass * 64 + kq * 4] = v4;
      }
    }
  }
}

// ---------------- K2: in-place row softmax (+ optional bf16 P copy) -----
template <int WRITE_PB>
__global__ __launch_bounds__(256) void k_softmax(float* __restrict__ S,
                                                 u16* __restrict__ Pb) {
  const int row = blockIdx.x;
  float* p = S + (size_t)row * N;
  const int tid = threadIdx.x;
  const int wid = tid >> 6, lane = tid & 63;
  __shared__ float red[4];

  float4 v[8];
  float m = -INFINITY;
#pragma unroll
  for (int i = 0; i < 8; ++i) {
    int idx = i * 256 + tid;
    float4 x = ((const float4*)p)[idx];
    if ((row >> 2) == idx) ((float*)&x)[row & 3] = -INFINITY;
    v[i] = x;
    m = fmaxf(m, fmaxf(fmaxf(x.x, x.y), fmaxf(x.z, x.w)));
  }
#pragma unroll
  for (int off = 32; off > 0; off >>= 1) m = fmaxf(m, __shfl_xor(m, off));
  if (lane == 0) red[wid] = m;
  __syncthreads();
  m = fmaxf(fmaxf(red[0], red[1]), fmaxf(red[2], red[3]));

  float s = 0.f;
#pragma unroll
  for (int i = 0; i < 8; ++i) {
    float4 e;
    e.x = __expf(v[i].x - m);
    e.y = __expf(v[i].y - m);
    e.z = __expf(v[i].z - m);
    e.w = __expf(v[i].w - m);
    v[i] = e;
    s += e.x + e.y + e.z + e.w;
  }
#pragma unroll
  for (int off = 32; off > 0; off >>= 1) s += __shfl_xor(s, off);
  __syncthreads();
  if (lane == 0) red[wid] = s;
  __syncthreads();
  s = red[0] + red[1] + red[2] + red[3];
  float inv = 1.0f / s;
#pragma unroll
  for (int i = 0; i < 8; ++i) {
    int idx = i * 256 + tid;
    float4 x = v[i];
    x.x *= inv; x.y *= inv; x.z *= inv; x.w *= inv;
    ((float4*)p)[idx] = x;
    if (WRITE_PB) {
      ushort4 h = {f2bf(x.x), f2bf(x.y), f2bf(x.z), f2bf(x.w)};
      ((ushort4*)(Pb + (size_t)row * N))[idx] = h;
    }
  }
}

// -------- K3: out = P @ X. DEEP PIPELINE (3 tiles ahead): ---------------
// A: Pb via gload_lds into As[4] slots; B: asm-pinned regs B0/B1/B2 from
// XTf (unroll-by-3 for static names). Issue(it+3) after compute(it) ->
// issue-to-consume distance ~2 iterations >> L2 latency. WAITV(12) steady.
__global__ __launch_bounds__(256) void k_pv(const u16* __restrict__ Pb,
                                            const u16* __restrict__ XTf,
                                            float* __restrict__ Out) {
  __shared__ u16 As[4][128 * 32];   // 32 KiB
  const int tid = threadIdx.x, wid = tid >> 6, lane = tid & 63;

  // XCD chunk swizzle over 512 blocks (q=64, bijective)
  int o = blockIdx.x;
  int l = (o & 7) * 64 + (o >> 3);
  const int brow = (l >> 3) * 128;
  const int bcol = (l & 7) * 128;

  const int wr = wid >> 1, wc = wid & 1;   // 2x2 waves, 64x64 each
  const int fr = lane & 15;
  const int c0 = lane >> 4;

  const char* pB = (const char*)XTf + (size_t)(bcol / 16 + wc * 4) * 1024 + lane * 16;

  f32x4 acc[4][4] = {};

#define STAGEA(t) do {                                                     \
    _Pragma("unroll")                                                      \
    for (int c = 0; c < 2; ++c) {                                          \
      int chunk = wid * 2 + c;                                             \
      int ebyte = chunk * 1024 + lane * 16;                                \
      int row = ebyte >> 6;                                                \
      int pc = (ebyte >> 4) & 3;                                           \
      int col = (pc ^ ((row >> 1) & 3)) * 8;                               \
      gload_lds16(Pb + (size_t)(brow + row) * N + (size_t)(t) * 32 + col,  \
                  (const char*)As[(t) & 3] + ebyte);                       \
    }                                                                      \
  } while (0)

#define LOADB(BUF, t) do {                                                 \
    const char* b_ = pB + ((size_t)(t) << 16);                             \
    ALOAD(BUF[0], b_);                                                     \
    ALOAD(BUF[1], b_ + 1024);                                              \
    ALOAD(BUF[2], b_ + 2048);                                              \
    ALOAD(BUF[3], b_ + 3072);                                              \
  } while (0)

#define PV_COMPUTE(s, BUF) do {                                            \
    bf16x8 a[4];                                                           \
    _Pragma("unroll")                                                      \
    for (int m = 0; m < 4; ++m) {                                          \
      int row = wr * 64 + m * 16 + fr;                                     \
      a[m] = *(const bf16x8*)((const char*)As[s] + swz_byte(row, c0));     \
    }                                                                      \
    PRIO(1);                                                               \
    _Pragma("unroll")                                                      \
    for (int m = 0; m < 4; ++m)                                            \
      _Pragma("unroll")                                                    \
      for (int n = 0; n < 4; ++n)                                          \
        acc[m][n] = __builtin_amdgcn_mfma_f32_16x16x32_bf16(a[m], BUF[n], acc[m][n], 0, 0, 0); \
    PRIO(0);                                                               \
  } while (0)

// One steady-state step: retire tile `it`'s 6 loads (12 newer stay in
// flight), compute it, then issue tile it+3 into the just-freed B buffer.
#define STEP(it, BUF) do {                                                 \
    WAITV(12);                                                             \
    SB();                                                                  \
    BAR();                                                                 \
    PV_COMPUTE((it) & 3, BUF);                                             \
    BAR();                                                                 \
    STAGEA((it) + 3);                                                      \
    LOADB(BUF, (it) + 3);                                                  \
    SB();                                                                  \
  } while (0)

  bf16x8 B0[4], B1[4], B2[4];   // asm-pinned rotation buffers

  STAGEA(0); LOADB(B0, 0);
  STAGEA(1); LOADB(B1, 1);
  STAGEA(2); LOADB(B2, 2);      // 18 loads outstanding
  SB();

  for (int t = 0; t < 84; ++t) {   // it = 3t .. 3t+2, covers 0..251
    int it = t * 3;
    STEP(it, B0);
    STEP(it + 1, B1);
    STEP(it + 2, B2);
  }
  STEP(252, B0);                 // issues tile 255 into B0
  // tail: no more issues; drain 12 -> 6 -> 0
  WAITV(12); SB(); BAR();
  PV_COMPUTE(253 & 3, B1);
  BAR();
  WAITV(6); SB(); BAR();
  PV_COMPUTE(254 & 3, B2);
  BAR();
  WAITV(0); SB(); BAR();
  PV_COMPUTE(255 & 3, B0);

#undef STEP
#undef STAGEA
#undef LOADB
#undef PV_COMPUTE

  const int rr = (lane >> 4) * 4;
#pragma unroll
  for (int m = 0; m < 4; ++m)
#pragma unroll
    for (int n = 0; n < 4; ++n)
#pragma unroll
      for (int r = 0; r < 4; ++r) {
        int row = brow + wr * 64 + m * 16 + rr + r;
        int col = bcol + wc * 64 + n * 16 + fr;
        Out[(size_t)row * D + col] = acc[m][n][r];
      }
}

// -------- K3 fallback: out = P @ X from fp32 P (row-major XT) -----------
__global__ __launch_bounds__(512) void k_pv_f32(const float* __restrict__ P,
                                                const u16* __restrict__ XT,
                                                float* __restrict__ Out) {
  __shared__ u16 As[128 * 32];
  __shared__ u16 Bs[256 * 32];
  const int tid = threadIdx.x, wid = tid >> 6, lane = tid & 63;
  const int brow = blockIdx.y * 128;
  const int bcol = blockIdx.x * 256;
  const int wr = wid >> 2, wc = wid & 3;
  const int fr = lane & 15;
  const int c0 = lane >> 4;

  f32x4 acc[4][4] = {};

  for (int kt = 0; kt < N; kt += 32) {
    __syncthreads();
#pragma unroll
    for (int c = 0; c < 2; ++c) {
      int chunk = wid * 2 + c;
      int ebyte = chunk * 1024 + lane * 16;
      int row = ebyte >> 6;
      int pc = (ebyte >> 4) & 3;
      int col = (pc ^ ((row >> 1) & 3)) * 8;
      gload_lds16(XT + (size_t)(bcol + row) * N + kt + col, (const char*)Bs + ebyte);
    }
#pragma unroll
    for (int i = 0; i < 2; ++i) {
      int idx = i * 512 + tid;
      int e = idx * 4;
      int row = e >> 5, col = e & 31;
      float4 x = *(const float4*)(P + (size_t)(brow + row) * N + kt + col);
      ushort4 h = {f2bf(x.x), f2bf(x.y), f2bf(x.z), f2bf(x.w)};
      int inner = (col * 2) ^ (((row >> 1) & 3) << 4);
      *(ushort4*)((char*)As + row * 64 + inner) = h;
    }
    __syncthreads();

    bf16x8 a[4], b[4];
#pragma unroll
    for (int m = 0; m < 4; ++m) {
      int row = wr * 64 + m * 16 + fr;
      a[m] = *(const bf16x8*)((const char*)As + swz_byte(row, c0));
    }
#pragma unroll
    for (int n = 0; n < 4; ++n) {
      int row = wc * 64 + n * 16 + fr;
      b[n] = *(const bf16x8*)((const char*)Bs + swz_byte(row, c0));
    }
#pragma unroll
    for (int m = 0; m < 4; ++m)
#pragma unroll
      for (int n = 0; n < 4; ++n)
        acc[m][n] = __builtin_amdgcn_mfma_f32_16x16x32_bf16(a[m], b[n], acc[m][n], 0, 0, 0);
  }

  const int rr = (lane >> 4) * 4;
#pragma unroll
  for (int m = 0; m < 4; ++m)
#pragma unroll
    for (int n = 0; n < 4; ++n)
#pragma unroll
      for (int r = 0; r < 4; ++r) {
        int row = brow + wr * 64 + m * 16 + rr + r;
        int col = bcol + wc * 64 + n * 16 + fr;
        Out[(size_t)row * D + col] = acc[m][n][r];
      }
}

extern "C" void kernel_launch(void* const* d_in, const int* in_sizes, int n_in,
                              void* d_out, int out_size, void* d_ws, size_t ws_size,
                              hipStream_t stream) {
  const float* X = (const float*)d_in[0];
  float* out = (float*)d_out;
  float* attn = out + (size_t)N * D;        // second output: raw S, then softmaxed

  u16* Xf = (u16*)d_ws;                     // 32 MB (frag-major hi|lo)
  u16* XT = Xf + (size_t)2 * N * D;         // 16 MB (XTf frag-major, or row-major)
  u16* Pb = XT + (size_t)N * D;             // 128 MB (optional)
  const bool usePb =
      ws_size >= ((size_t)N * D * 3 + (size_t)N * N) * sizeof(u16);

  k_split<<<(N * D / 8) / 256, 256, 0, stream>>>(X, Xf);
  k_qkt<<<64 * 65 / 2, 256, 0, stream>>>(Xf, attn);
  if (usePb) {
    k_xt<1><<<dim3(D / 32, N / 32), 256, 0, stream>>>(X, XT);
    k_softmax<1><<<N, 256, 0, stream>>>(attn, Pb);
    k_pv<<<512, 256, 0, stream>>>(Pb, XT, out);
  } else {
    k_xt<0><<<dim3(D / 32, N / 32), 256, 0, stream>>>(X, XT);
    k_softmax<0><<<N, 256, 0, stream>>>(attn, nullptr);
    k_pv_f32<<<dim3(D / 256, N / 128), 512, 0, stream>>>(attn, XT, out);
  }
}

// Round 13
// 556.214 us; speedup vs baseline: 1.2604x; 1.0518x over previous
//
#include <hip/hip_runtime.h>

#define N 8192
#define D 1024

typedef short bf16x8 __attribute__((ext_vector_type(8)));
typedef float f32x4 __attribute__((ext_vector_type(4)));
typedef unsigned short u16;

#define WAITV(n) asm volatile("s_waitcnt vmcnt(" #n ")" ::: "memory")
#define BAR() __builtin_amdgcn_s_barrier()
#define SB() __builtin_amdgcn_sched_barrier(0)
#define PRIO(p) __builtin_amdgcn_s_setprio(p)

// Opaque asm load: compiler cannot sink it toward its consumer, so the
// 3-deep register pipeline actually materializes. vmcnt managed manually.
#define ALOAD(d, p) \
  asm volatile("global_load_dwordx4 %0, %1, off" : "=&v"(d) : "v"(p))

__device__ __forceinline__ u16 f2bf(float f) {
  unsigned u = __float_as_uint(f);
  u += 0x7FFF + ((u >> 16) & 1);   // RNE to bf16
  return (u16)(u >> 16);
}
__device__ __forceinline__ float bf2f(u16 h) {
  return __uint_as_float(((unsigned)h) << 16);
}

__device__ __forceinline__ void gload_lds16(const void* g, const void* l) {
  __builtin_amdgcn_global_load_lds(
      (const __attribute__((address_space(1))) void*)g,
      (__attribute__((address_space(3))) void*)l, 16, 0, 0);
}

// Swizzled [rows][32] bf16 LDS tile (pv A-staging): 64 B/row, 4x16B chunks.
__device__ __forceinline__ int swz_byte(int row, int logical_chunk) {
  return row * 64 + ((logical_chunk ^ ((row >> 1) & 3)) << 4);
}

// Fragment-major X layouts:
//  Xf (qkt): tile (rt=r>>4, kt=k>>5) at (rt*32+kt)*2048; hi 1KB then lo 1KB.
//    lane-in-tile = (r&15) + 16*((k>>3)&3), 16 B each. rt stride 65536 B.
//  XTf (pv B): tile (kt=k>>5, dt=d>>4) at (kt*64+dt)*1024; kt stride 65536 B.

// ---------------- K0: split X (fp32) into frag-major hi|lo bf16 ---------
__global__ __launch_bounds__(256) void k_split(const float* __restrict__ X,
                                               u16* __restrict__ Xf) {
  int i = blockIdx.x * 256 + threadIdx.x;   // [0, N*D/8)
  int r = i >> 7;
  int kc = (i & 127) << 3;
  float4 x0 = *(const float4*)(X + (size_t)r * D + kc);
  float4 x1 = *(const float4*)(X + (size_t)r * D + kc + 4);
  float xs[8] = {x0.x, x0.y, x0.z, x0.w, x1.x, x1.y, x1.z, x1.w};
  u16 h[8], lo[8];
#pragma unroll
  for (int j = 0; j < 8; ++j) {
    h[j] = f2bf(xs[j]);
    lo[j] = f2bf(xs[j] - bf2f(h[j]));
  }
  size_t fb = (size_t)((r >> 4) * 32 + (kc >> 5)) * 2048;
  int lbyte = ((r & 15) + ((kc >> 3) & 3) * 16) * 16;
  *(int4*)((char*)Xf + fb + lbyte) = *(int4*)h;
  *(int4*)((char*)Xf + fb + 1024 + lbyte) = *(int4*)lo;
}

// ------ K0b: X (fp32) -> XTf frag-major (FRAG=1) or XT row-major (0) ----
template <int FRAG>
__global__ __launch_bounds__(256) void k_xt(const float* __restrict__ X,
                                            u16* __restrict__ XT) {
  __shared__ u16 t[32][33];
  const int jt = blockIdx.y * 32, dt = blockIdx.x * 32;
  const int c = threadIdx.x & 31, rg = threadIdx.x >> 5;   // rg in 0..7
#pragma unroll
  for (int k = 0; k < 4; ++k) {
    int r = rg * 4 + k;
    t[r][c] = f2bf(X[(size_t)(jt + r) * D + dt + c]);
  }
  __syncthreads();
  if (FRAG) {
    if (threadIdx.x < 128) {
      int dg = dt + (threadIdx.x & 31);
      int jg = jt + (threadIdx.x >> 5) * 8;
      u16 v[8];
#pragma unroll
      for (int e = 0; e < 8; ++e) v[e] = t[(threadIdx.x >> 5) * 8 + e][threadIdx.x & 31];
      size_t tile = (size_t)(jg >> 5) * 64 + (dg >> 4);
      int lane16 = (dg & 15) + 16 * ((jg >> 3) & 3);
      *(int4*)((char*)XT + (tile << 10) + lane16 * 16) = *(int4*)v;
    }
  } else {
#pragma unroll
    for (int k = 0; k < 4; ++k) {
      int d = rg * 4 + k;
      XT[(size_t)(dt + d) * N + jt + c] = t[c][d];
    }
  }
}

// ------- K1: S = X X^T, symmetric upper-tri 128x128 blocks --------------
// Fragment-direct global->VGPR (R9 structure) + SQUARE-CLUSTERED ordering:
// each XCD's contiguous chunk walks 8x8-block squares so the ~48 blocks
// concurrently resident per XCD touch ~16 panels (8 MB) instead of ~25 MB
// -> fewer L2 misses (the measured wall).
__global__ __launch_bounds__(256) void k_qkt(const u16* __restrict__ Xf,
                                             float* __restrict__ S) {
  __shared__ float tbuf[128][64];   // epilogue transpose bounce only (32 KiB)
  const int tid = threadIdx.x, wid = tid >> 6, lane = tid & 63;

  // XCD chunk swizzle over 2080 blocks (2080 = 8 * 260, bijective)
  int o = blockIdx.x;
  int L = (o & 7) * 260 + (o >> 3);
  // square-clustered mapping: rows of 8x8 squares; row si has one diagonal
  // square (36 tiles) + (7-si) full squares (64 tiles each)
  int si = 0, rem = L;
  while (rem >= 36 + (7 - si) * 64) { rem -= 36 + (7 - si) * 64; ++si; }
  int bi, bj;
  if (rem < 36) {                       // diagonal square (si, si)
    int i = 0;
    while (rem >= 8 - i) { rem -= 8 - i; ++i; }
    bi = si * 8 + i;
    bj = si * 8 + i + rem;
  } else {                              // full square (si, sj), sj > si
    rem -= 36;
    int sj = si + 1 + (rem >> 6);
    int r = rem & 63;
    bi = si * 8 + (r >> 3);
    bj = sj * 8 + (r & 7);
  }
  const int brow = bi * 128, bcol = bj * 128;

  const int wr = wid >> 1, wc = wid & 1;
  const int fr = lane & 15;

  const char* Xfc = (const char*)Xf;
  const char* pA = Xfc + (size_t)(brow / 16 + wr * 4) * 65536 + lane * 16;
  const char* pB = Xfc + (size_t)(bcol / 16 + wc * 4) * 65536 + lane * 16;

  f32x4 acc[4][4] = {};

#define LOADF(P, kt) do {                                                  \
    _Pragma("unroll")                                                      \
    for (int m = 0; m < 4; ++m) {                                          \
      const char* a_ = pA + (size_t)m * 65536 + (size_t)(kt) * 2048;       \
      const char* b_ = pB + (size_t)m * 65536 + (size_t)(kt) * 2048;       \
      P##ah[m] = *(const bf16x8*)a_;                                       \
      P##al[m] = *(const bf16x8*)(a_ + 1024);                              \
      P##bh[m] = *(const bf16x8*)b_;                                       \
      P##bl[m] = *(const bf16x8*)(b_ + 1024);                              \
    }                                                                      \
  } while (0)

#define FMAF(P) do {                                                       \
    PRIO(1);                                                               \
    _Pragma("unroll")                                                      \
    for (int m = 0; m < 4; ++m)                                            \
      _Pragma("unroll")                                                    \
      for (int n = 0; n < 4; ++n) {                                        \
        acc[m][n] = __builtin_amdgcn_mfma_f32_16x16x32_bf16(P##ah[m], P##bh[n], acc[m][n], 0, 0, 0); \
        acc[m][n] = __builtin_amdgcn_mfma_f32_16x16x32_bf16(P##ah[m], P##bl[n], acc[m][n], 0, 0, 0); \
        acc[m][n] = __builtin_amdgcn_mfma_f32_16x16x32_bf16(P##al[m], P##bh[n], acc[m][n], 0, 0, 0); \
      }                                                                    \
    PRIO(0);                                                               \
  } while (0)

  bf16x8 Aah[4], Aal[4], Abh[4], Abl[4];   // buffer A
  bf16x8 Bah[4], Bal[4], Bbh[4], Bbl[4];   // buffer B

  LOADF(A, 0);
  SB();
  for (int kt = 0; kt < 30; kt += 2) {
    LOADF(B, kt + 1);
    SB();
    FMAF(A);
    LOADF(A, kt + 2);
    SB();
    FMAF(B);
  }
  LOADF(B, 31);
  SB();
  FMAF(A);
  FMAF(B);

#undef LOADF
#undef FMAF

  const int rr = (lane >> 4) * 4;
  // direct tile write: S[brow..][bcol..]
#pragma unroll
  for (int m = 0; m < 4; ++m)
#pragma unroll
    for (int n = 0; n < 4; ++n)
#pragma unroll
      for (int r = 0; r < 4; ++r) {
        int row = brow + wr * 64 + m * 16 + rr + r;
        int col = bcol + wc * 64 + n * 16 + fr;
        S[(size_t)row * N + col] = acc[m][n][r];
      }

  // transposed tile write for off-diagonal blocks: S[bcol..][brow..]
  if (bi != bj) {
#pragma unroll
    for (int pass = 0; pass < 2; ++pass) {
      __syncthreads();
      if (wr == pass) {
#pragma unroll
        for (int m = 0; m < 4; ++m)
#pragma unroll
          for (int n = 0; n < 4; ++n) {
            f32x4 v = acc[m][n];
            int c = wc * 64 + n * 16 + fr;
            int inner = ((m * 16 + rr) * 4) ^ ((c & 15) << 4);
            *(f32x4*)((char*)&tbuf[c][0] + inner) = v;
          }
      }
      __syncthreads();
#pragma unroll
      for (int i = 0; i < 8; ++i) {
        int idx = i * 256 + tid;         // 2048 float4 = 128 cols x 16 quads
        int c = idx >> 4;
        int kq = idx & 15;
        int inner = (kq * 16) ^ ((c & 15) << 4);
        float4 v4 = *(const float4*)((const char*)&tbuf[c][0] + inner);
        *(float4*)&S[(size_t)(bcol + c) * N + brow + pass * 64 + kq * 4] = v4;
      }
    }
  }
}

// ---------------- K2: in-place row softmax (+ optional bf16 P copy) -----
template <int WRITE_PB>
__global__ __launch_bounds__(256) void k_softmax(float* __restrict__ S,
                                                 u16* __restrict__ Pb) {
  const int row = blockIdx.x;
  float* p = S + (size_t)row * N;
  const int tid = threadIdx.x;
  const int wid = tid >> 6, lane = tid & 63;
  __shared__ float red[4];

  float4 v[8];
  float m = -INFINITY;
#pragma unroll
  for (int i = 0; i < 8; ++i) {
    int idx = i * 256 + tid;
    float4 x = ((const float4*)p)[idx];
    if ((row >> 2) == idx) ((float*)&x)[row & 3] = -INFINITY;
    v[i] = x;
    m = fmaxf(m, fmaxf(fmaxf(x.x, x.y), fmaxf(x.z, x.w)));
  }
#pragma unroll
  for (int off = 32; off > 0; off >>= 1) m = fmaxf(m, __shfl_xor(m, off));
  if (lane == 0) red[wid] = m;
  __syncthreads();
  m = fmaxf(fmaxf(red[0], red[1]), fmaxf(red[2], red[3]));

  float s = 0.f;
#pragma unroll
  for (int i = 0; i < 8; ++i) {
    float4 e;
    e.x = __expf(v[i].x - m);
    e.y = __expf(v[i].y - m);
    e.z = __expf(v[i].z - m);
    e.w = __expf(v[i].w - m);
    v[i] = e;
    s += e.x + e.y + e.z + e.w;
  }
#pragma unroll
  for (int off = 32; off > 0; off >>= 1) s += __shfl_xor(s, off);
  __syncthreads();
  if (lane == 0) red[wid] = s;
  __syncthreads();
  s = red[0] + red[1] + red[2] + red[3];
  float inv = 1.0f / s;
#pragma unroll
  for (int i = 0; i < 8; ++i) {
    int idx = i * 256 + tid;
    float4 x = v[i];
    x.x *= inv; x.y *= inv; x.z *= inv; x.w *= inv;
    ((float4*)p)[idx] = x;
    if (WRITE_PB) {
      ushort4 h = {f2bf(x.x), f2bf(x.y), f2bf(x.z), f2bf(x.w)};
      ((ushort4*)(Pb + (size_t)row * N))[idx] = h;
    }
  }
}

// -------- K3: out = P @ X. BM=128, BN=256, 512 thr, deep pipeline -------
// Halves Pb re-reads vs BN=128 (D/BN = 4 col-blocks). A: Pb via gload_lds
// into As[4]; B: asm-pinned B0/B1/B2 from XTf. 5 vmem/step/wave ->
// WAITV(10) steady, drain 10 -> 5 -> 0.
__global__ __launch_bounds__(512) void k_pv(const u16* __restrict__ Pb,
                                            const u16* __restrict__ XTf,
                                            float* __restrict__ Out) {
  __shared__ u16 As[4][128 * 32];   // 32 KiB
  const int tid = threadIdx.x, wid = tid >> 6, lane = tid & 63;

  // XCD chunk swizzle over 256 blocks (q=32, bijective): per XCD
  // 8 brow x 4 bcol, so Pb panels are shared by the 4 resident bcol-blocks.
  int o = blockIdx.x;
  int l = (o & 7) * 32 + (o >> 3);
  const int brow = (l >> 2) * 128;
  const int bcol = (l & 3) * 256;

  const int wr = wid >> 2, wc = wid & 3;   // 2x4 waves, 64x64 each
  const int fr = lane & 15;
  const int c0 = lane >> 4;

  const char* pB = (const char*)XTf + (size_t)(bcol / 16 + wc * 4) * 1024 + lane * 16;

  f32x4 acc[4][4] = {};

#define STAGEA(t) do {                                                     \
    int ebyte = wid * 1024 + lane * 16;                                    \
    int row = ebyte >> 6;                                                  \
    int pc = (ebyte >> 4) & 3;                                             \
    int col = (pc ^ ((row >> 1) & 3)) * 8;                                 \
    gload_lds16(Pb + (size_t)(brow + row) * N + (size_t)(t) * 32 + col,    \
                (const char*)As[(t) & 3] + ebyte);                         \
  } while (0)

#define LOADB(BUF, t) do {                                                 \
    const char* b_ = pB + ((size_t)(t) << 16);                             \
    ALOAD(BUF[0], b_);                                                     \
    ALOAD(BUF[1], b_ + 1024);                                              \
    ALOAD(BUF[2], b_ + 2048);                                              \
    ALOAD(BUF[3], b_ + 3072);                                              \
  } while (0)

#define PV_COMPUTE(s, BUF) do {                                            \
    bf16x8 a[4];                                                           \
    _Pragma("unroll")                                                      \
    for (int m = 0; m < 4; ++m) {                                          \
      int row = wr * 64 + m * 16 + fr;                                     \
      a[m] = *(const bf16x8*)((const char*)As[s] + swz_byte(row, c0));     \
    }                                                                      \
    PRIO(1);                                                               \
    _Pragma("unroll")                                                      \
    for (int m = 0; m < 4; ++m)                                            \
      _Pragma("unroll")                                                    \
      for (int n = 0; n < 4; ++n)                                          \
        acc[m][n] = __builtin_amdgcn_mfma_f32_16x16x32_bf16(a[m], BUF[n], acc[m][n], 0, 0, 0); \
    PRIO(0);                                                               \
  } while (0)

// One steady-state step: retire tile `it`'s 5 loads (10 newer stay in
// flight), compute it, then issue tile it+3 into the just-freed B buffer.
#define STEP(it, BUF) do {                                                 \
    WAITV(10);                                                             \
    SB();                                                                  \
    BAR();                                                                 \
    PV_COMPUTE((it) & 3, BUF);                                             \
    BAR();                                                                 \
    STAGEA((it) + 3);                                                      \
    LOADB(BUF, (it) + 3);                                                  \
    SB();                                                                  \
  } while (0)

  bf16x8 B0[4], B1[4], B2[4];   // asm-pinned rotation buffers

  STAGEA(0); LOADB(B0, 0);
  STAGEA(1); LOADB(B1, 1);
  STAGEA(2); LOADB(B2, 2);      // 15 loads/wave outstanding
  SB();

  for (int t = 0; t < 84; ++t) {   // it = 3t .. 3t+2, covers 0..251
    int it = t * 3;
    STEP(it, B0);
    STEP(it + 1, B1);
    STEP(it + 2, B2);
  }
  STEP(252, B0);                 // issues tile 255 into B0
  // tail: no more issues; drain 10 -> 5 -> 0
  WAITV(10); SB(); BAR();
  PV_COMPUTE(253 & 3, B1);
  BAR();
  WAITV(5); SB(); BAR();
  PV_COMPUTE(254 & 3, B2);
  BAR();
  WAITV(0); SB(); BAR();
  PV_COMPUTE(255 & 3, B0);

#undef STEP
#undef STAGEA
#undef LOADB
#undef PV_COMPUTE

  const int rr = (lane >> 4) * 4;
#pragma unroll
  for (int m = 0; m < 4; ++m)
#pragma unroll
    for (int n = 0; n < 4; ++n)
#pragma unroll
      for (int r = 0; r < 4; ++r) {
        int row = brow + wr * 64 + m * 16 + rr + r;
        int col = bcol + wc * 64 + n * 16 + fr;
        Out[(size_t)row * D + col] = acc[m][n][r];
      }
}

// -------- K3 fallback: out = P @ X from fp32 P (row-major XT) -----------
__global__ __launch_bounds__(512) void k_pv_f32(const float* __restrict__ P,
                                                const u16* __restrict__ XT,
                                                float* __restrict__ Out) {
  __shared__ u16 As[128 * 32];
  __shared__ u16 Bs[256 * 32];
  const int tid = threadIdx.x, wid = tid >> 6, lane = tid & 63;
  const int brow = blockIdx.y * 128;
  const int bcol = blockIdx.x * 256;
  const int wr = wid >> 2, wc = wid & 3;
  const int fr = lane & 15;
  const int c0 = lane >> 4;

  f32x4 acc[4][4] = {};

  for (int kt = 0; kt < N; kt += 32) {
    __syncthreads();
#pragma unroll
    for (int c = 0; c < 2; ++c) {
      int chunk = wid * 2 + c;
      int ebyte = chunk * 1024 + lane * 16;
      int row = ebyte >> 6;
      int pc = (ebyte >> 4) & 3;
      int col = (pc ^ ((row >> 1) & 3)) * 8;
      gload_lds16(XT + (size_t)(bcol + row) * N + kt + col, (const char*)Bs + ebyte);
    }
#pragma unroll
    for (int i = 0; i < 2; ++i) {
      int idx = i * 512 + tid;
      int e = idx * 4;
      int row = e >> 5, col = e & 31;
      float4 x = *(const float4*)(P + (size_t)(brow + row) * N + kt + col);
      ushort4 h = {f2bf(x.x), f2bf(x.y), f2bf(x.z), f2bf(x.w)};
      int inner = (col * 2) ^ (((row >> 1) & 3) << 4);
      *(ushort4*)((char*)As + row * 64 + inner) = h;
    }
    __syncthreads();

    bf16x8 a[4], b[4];
#pragma unroll
    for (int m = 0; m < 4; ++m) {
      int row = wr * 64 + m * 16 + fr;
      a[m] = *(const bf16x8*)((const char*)As + swz_byte(row, c0));
    }
#pragma unroll
    for (int n = 0; n < 4; ++n) {
      int row = wc * 64 + n * 16 + fr;
      b[n] = *(const bf16x8*)((const char*)Bs + swz_byte(row, c0));
    }
#pragma unroll
    for (int m = 0; m < 4; ++m)
#pragma unroll
      for (int n = 0; n < 4; ++n)
        acc[m][n] = __builtin_amdgcn_mfma_f32_16x16x32_bf16(a[m], b[n], acc[m][n], 0, 0, 0);
  }

  const int rr = (lane >> 4) * 4;
#pragma unroll
  for (int m = 0; m < 4; ++m)
#pragma unroll
    for (int n = 0; n < 4; ++n)
#pragma unroll
      for (int r = 0; r < 4; ++r) {
        int row = brow + wr * 64 + m * 16 + rr + r;
        int col = bcol + wc * 64 + n * 16 + fr;
        Out[(size_t)row * D + col] = acc[m][n][r];
      }
}

extern "C" void kernel_launch(void* const* d_in, const int* in_sizes, int n_in,
                              void* d_out, int out_size, void* d_ws, size_t ws_size,
                              hipStream_t stream) {
  const float* X = (const float*)d_in[0];
  float* out = (float*)d_out;
  float* attn = out + (size_t)N * D;        // second output: raw S, then softmaxed

  u16* Xf = (u16*)d_ws;                     // 32 MB (frag-major hi|lo)
  u16* XT = Xf + (size_t)2 * N * D;         // 16 MB (XTf frag-major, or row-major)
  u16* Pb = XT + (size_t)N * D;             // 128 MB (optional)
  const bool usePb =
      ws_size >= ((size_t)N * D * 3 + (size_t)N * N) * sizeof(u16);

  k_split<<<(N * D / 8) / 256, 256, 0, stream>>>(X, Xf);
  k_qkt<<<64 * 65 / 2, 256, 0, stream>>>(Xf, attn);
  if (usePb) {
    k_xt<1><<<dim3(D / 32, N / 32), 256, 0, stream>>>(X, XT);
    k_softmax<1><<<N, 256, 0, stream>>>(attn, Pb);
    k_pv<<<256, 512, 0, stream>>>(Pb, XT, out);
  } else {
    k_xt<0><<<dim3(D / 32, N / 32), 256, 0, stream>>>(X, XT);
    k_softmax<0><<<N, 256, 0, stream>>>(attn, nullptr);
    k_pv_f32<<<dim3(D / 256, N / 128), 512, 0, stream>>>(attn, XT, out);
  }
}